// Round 1
// baseline (256.539 us; speedup 1.0000x reference)
//
#include <hip/hip_runtime.h>

// ---------------------------------------------------------------------------
// PlaneEmbeddingNetwork: per-face (F=500K) attention over E=4 tokens, D=16,
// H=2 heads of 8, then folded MLP + mean-pool + output proj.
// Design: ONE THREAD PER FACE. All weight indices are wave-uniform -> s_load
// (SMEM pipe), so the VALU does ~7.1K fma/face with no LDS weight traffic.
// ---------------------------------------------------------------------------

// Setup kernel: W1 = w_out @ fc_w  [16x32] -> ws[0..511]
//               b1 = b_out @ fc_w + fc_b [32] -> ws[512..543]
__global__ void fold_w1(const float* __restrict__ w_out,
                        const float* __restrict__ b_out,
                        const float* __restrict__ fc_w,
                        const float* __restrict__ fc_b,
                        float* __restrict__ ws) {
    int tid = threadIdx.x;
    if (tid < 512) {
        int d = tid >> 5, c = tid & 31;
        float acc = 0.f;
#pragma unroll
        for (int e = 0; e < 16; ++e)
            acc = fmaf(w_out[d * 16 + e], fc_w[e * 32 + c], acc);
        ws[tid] = acc;
    } else if (tid < 544) {
        int c = tid - 512;
        float acc = fc_b[c];
#pragma unroll
        for (int e = 0; e < 16; ++e)
            acc = fmaf(b_out[e], fc_w[e * 32 + c], acc);
        ws[tid] = acc;
    }
}

__launch_bounds__(256, 2)
__global__ void face_net(const float* __restrict__ node,
                         const int*   __restrict__ fids,
                         const float* __restrict__ w_in,
                         const float* __restrict__ b_in,
                         const float* __restrict__ w1b1,   // ws: [512]=W1, [32]=b1
                         const float* __restrict__ fco_w,
                         const float* __restrict__ fco_b,
                         float* __restrict__ out, int F) {
    // LDS staging for pooled[32] per thread: layout pl[c*256 + tid]
    // -> bank = tid%32 for any c: 2-way (free) on both write and read.
    __shared__ float pl[32 * 256];

    const int f = blockIdx.x * 256 + threadIdx.x;
    if (f >= F) return;

    const int4 id4 = *reinterpret_cast<const int4*>(fids + (size_t)f * 4);
    const float* xp0 = node + (size_t)id4.x * 16;
    const float* xp1 = node + (size_t)id4.y * 16;
    const float* xp2 = node + (size_t)id4.z * 16;
    const float* xp3 = node + (size_t)id4.w * 16;

    // ---- qkv projection: q/k/v[t][16]. k-bias dropped (softmax row-const).
    float q[4][16], k[4][16], v[4][16];
#pragma unroll
    for (int o = 0; o < 16; ++o) {
        const float bq = b_in[o], bv = b_in[32 + o];
#pragma unroll
        for (int t = 0; t < 4; ++t) { q[t][o] = bq; k[t][o] = 0.f; v[t][o] = bv; }
    }

#pragma unroll
    for (int cc = 0; cc < 4; ++cc) {
        const float4 x0 = *reinterpret_cast<const float4*>(xp0 + cc * 4);
        const float4 x1 = *reinterpret_cast<const float4*>(xp1 + cc * 4);
        const float4 x2 = *reinterpret_cast<const float4*>(xp2 + cc * 4);
        const float4 x3 = *reinterpret_cast<const float4*>(xp3 + cc * 4);
        const float xa[4][4] = {{x0.x, x0.y, x0.z, x0.w},
                                {x1.x, x1.y, x1.z, x1.w},
                                {x2.x, x2.y, x2.z, x2.w},
                                {x3.x, x3.y, x3.z, x3.w}};
#pragma unroll
        for (int dd = 0; dd < 4; ++dd) {
            const float* wrow = w_in + (cc * 4 + dd) * 48;  // uniform -> s_load
#pragma unroll
            for (int o = 0; o < 16; ++o) {
                const float wq = wrow[o], wk = wrow[16 + o], wv = wrow[32 + o];
#pragma unroll
                for (int t = 0; t < 4; ++t) {
                    q[t][o] = fmaf(xa[t][dd], wq, q[t][o]);
                    k[t][o] = fmaf(xa[t][dd], wk, k[t][o]);
                    v[t][o] = fmaf(xa[t][dd], wv, v[t][o]);
                }
            }
        }
    }

    // ---- attention per head: scores -> softmax -> o_[t][16]
    float o_[4][16];
    const float scale = 0.35355339059327373f;  // 1/sqrt(8)
#pragma unroll
    for (int h = 0; h < 2; ++h) {
        const int hb = h * 8;
        float p[4][4];
#pragma unroll
        for (int t = 0; t < 4; ++t) {
#pragma unroll
            for (int j = 0; j < 4; ++j) {
                float s = 0.f;
#pragma unroll
                for (int dh = 0; dh < 8; ++dh)
                    s = fmaf(q[t][hb + dh], k[j][hb + dh], s);
                p[t][j] = s * scale;
            }
            const float m = fmaxf(fmaxf(p[t][0], p[t][1]), fmaxf(p[t][2], p[t][3]));
            float sum = 0.f;
#pragma unroll
            for (int j = 0; j < 4; ++j) { p[t][j] = __expf(p[t][j] - m); sum += p[t][j]; }
            const float r = __builtin_amdgcn_rcpf(sum);
#pragma unroll
            for (int j = 0; j < 4; ++j) p[t][j] *= r;
        }
#pragma unroll
        for (int t = 0; t < 4; ++t)
#pragma unroll
            for (int dh = 0; dh < 8; ++dh) {
                float acc = 0.f;
#pragma unroll
                for (int j = 0; j < 4; ++j)
                    acc = fmaf(p[t][j], v[j][hb + dh], acc);
                o_[t][hb + dh] = acc;
            }
    }

    // ---- pooled[c] = 0.25 * sum_t relu(o_[t] @ W1 + b1)   (rolled, via LDS)
    float* myp = pl + threadIdx.x;
#pragma unroll 1
    for (int cg = 0; cg < 8; ++cg) {
#pragma unroll
        for (int u = 0; u < 4; ++u) {
            const int c = cg * 4 + u;
            const float b1c = w1b1[512 + c];
            float s = 0.f;
#pragma unroll
            for (int t = 0; t < 4; ++t) {
                float hp = b1c;
#pragma unroll
                for (int d2 = 0; d2 < 16; ++d2)
                    hp = fmaf(o_[t][d2], w1b1[d2 * 32 + c], hp);
                s += fmaxf(hp, 0.f);
            }
            myp[c * 256] = s * 0.25f;
        }
    }

    // ---- out = pooled @ fco_w + fco_b   (rolled over c; fco_w row s_loaded)
    float oacc[32];
#pragma unroll
    for (int c2 = 0; c2 < 32; ++c2) oacc[c2] = fco_b[c2];
#pragma unroll 1
    for (int c = 0; c < 32; ++c) {
        const float pc = myp[c * 256];
        const float* wr = fco_w + c * 32;  // uniform -> s_load
#pragma unroll
        for (int c2 = 0; c2 < 32; ++c2)
            oacc[c2] = fmaf(pc, wr[c2], oacc[c2]);
    }

    float* op = out + (size_t)f * 32;
#pragma unroll
    for (int g = 0; g < 8; ++g) {
        const float4 w4 = make_float4(oacc[g * 4], oacc[g * 4 + 1],
                                      oacc[g * 4 + 2], oacc[g * 4 + 3]);
        *reinterpret_cast<float4*>(op + g * 4) = w4;
    }
}

extern "C" void kernel_launch(void* const* d_in, const int* in_sizes, int n_in,
                              void* d_out, int out_size, void* d_ws, size_t ws_size,
                              hipStream_t stream) {
    const float* node  = (const float*)d_in[0];
    const int*   fids  = (const int*)  d_in[1];
    const float* w_in  = (const float*)d_in[2];
    const float* b_in  = (const float*)d_in[3];
    const float* w_out = (const float*)d_in[4];
    const float* b_out = (const float*)d_in[5];
    const float* fc_w  = (const float*)d_in[6];
    const float* fc_b  = (const float*)d_in[7];
    const float* fco_w = (const float*)d_in[8];
    const float* fco_b = (const float*)d_in[9];
    float* out = (float*)d_out;
    float* ws  = (float*)d_ws;
    const int F = in_sizes[1] / 4;

    hipLaunchKernelGGL(fold_w1, dim3(1), dim3(576), 0, stream,
                       w_out, b_out, fc_w, fc_b, ws);
    const int blocks = (F + 255) / 256;
    hipLaunchKernelGGL(face_net, dim3(blocks), dim3(256), 0, stream,
                       node, fids, w_in, b_in, ws, fco_w, fco_b, out, F);
}